// Round 11
// baseline (915.182 us; speedup 1.0000x reference)
//
#include <hip/hip_runtime.h>
#include <cmath>

#define B_ROWS 16384
#define IN_DIM 784
#define N_HID  2000
#define K_WIN  200
#define KPAD   800
#define EPS_MARGIN 1.5e-3f

typedef __attribute__((ext_vector_type(8))) short bf16x8;            // 8 bf16 = 4 VGPR
typedef __attribute__((ext_vector_type(8))) unsigned short u16x8;    // 16 B
typedef __attribute__((ext_vector_type(4))) float floatx4;           // MFMA C/D

__device__ inline unsigned short bf16_rn_bits(float f) {
    unsigned u = __float_as_uint(f);
    return (unsigned short)((u + 0x7FFFu + ((u >> 16) & 1u)) >> 16);
}
__device__ inline unsigned mapkey(float f) {
    unsigned u = __float_as_uint(f);
    return (u >> 31) ? ~u : (u | 0x80000000u);
}
__device__ inline float unmapkey(unsigned k) {
    unsigned u = (k & 0x80000000u) ? (k & 0x7FFFFFFFu) : ~k;
    return __uint_as_float(u);
}

// ---------------------------------------------------------------------------
// Phase 0a: boost + w2 transpose
// ---------------------------------------------------------------------------
__global__ __launch_bounds__(256) void prep_kernel(const float* __restrict__ duty,
                                                   const float* __restrict__ w2,
                                                   float* __restrict__ boost,
                                                   float* __restrict__ w2t) {
    int t = blockIdx.x * 256 + threadIdx.x;
    if (t < N_HID) boost[t] = expf(0.1f - duty[t]);
    if (t < N_HID * 10) {
        int i = t / 10, c = t - i * 10;
        w2t[i * 12 + c] = w2[c * N_HID + i];
    }
}

// ---------------------------------------------------------------------------
// Phase 0b: one-time fp32 -> bf16 hi/lo split of x and w1 (K padded to 800).
// Split formula IDENTICAL to round 10's in-kernel split -> same bits.
// ---------------------------------------------------------------------------
#define XG (B_ROWS * (KPAD / 4))   // 3,276,800 float4-groups
#define WG (N_HID  * (KPAD / 4))   //   400,000
__global__ __launch_bounds__(256) void split_kernel(
        const float* __restrict__ x, const float* __restrict__ w1,
        unsigned short* __restrict__ xh, unsigned short* __restrict__ xl,
        unsigned short* __restrict__ wh, unsigned short* __restrict__ wl) {
    int t = blockIdx.x * 256 + threadIdx.x;
    const float* src;
    unsigned short *dh, *dl;
    int row, g;
    if (t < XG) {
        row = t / (KPAD / 4); g = t - row * (KPAD / 4);
        src = x + (size_t)row * IN_DIM;
        dh = xh + (size_t)row * KPAD; dl = xl + (size_t)row * KPAD;
    } else if (t < XG + WG) {
        int s = t - XG;
        row = s / (KPAD / 4); g = s - row * (KPAD / 4);
        src = w1 + (size_t)row * IN_DIM;
        dh = wh + (size_t)row * KPAD; dl = wl + (size_t)row * KPAD;
    } else return;
    const int kq = g * 4;
    float4 v = make_float4(0.f, 0.f, 0.f, 0.f);
    if (kq + 3 < IN_DIM) v = *(const float4*)(src + kq);   // kq multiple of 4; pad zeros
    const float* vp = (const float*)&v;
    unsigned short hs[4], ls[4];
    #pragma unroll
    for (int q = 0; q < 4; ++q) {
        hs[q] = bf16_rn_bits(vp[q]);
        float hf = __uint_as_float(((unsigned)hs[q]) << 16);
        ls[q] = bf16_rn_bits(vp[q] - hf);
    }
    *(ushort4*)(dh + kq) = make_ushort4(hs[0], hs[1], hs[2], hs[3]);
    *(ushort4*)(dl + kq) = make_ushort4(ls[0], ls[1], ls[2], ls[3]);
}

// ---------------------------------------------------------------------------
// Phase 1: h' = x @ W1^T + b1 via split-bf16 MFMA (hh + hl + lh), streaming
// PRE-SPLIT bf16 arrays (no split VALU in the hot loop).  Block 128x128,
// wave 64x64 = 4x4 MFMA 16x16x32 tiles, chunk K=32, register prefetch +
// 2-barrier pipeline.  Chunk order and product order identical to round 10
// -> h' bit-identical -> winner machinery unchanged.
// ---------------------------------------------------------------------------
__global__ __launch_bounds__(256) void gemm_mfma_kernel(
        const unsigned short* __restrict__ xh, const unsigned short* __restrict__ xl,
        const unsigned short* __restrict__ wh, const unsigned short* __restrict__ wl,
        const float* __restrict__ b1, float* __restrict__ h) {
    __shared__ unsigned short Ah[128][40] __attribute__((aligned(16)));
    __shared__ unsigned short Al[128][40] __attribute__((aligned(16)));
    __shared__ unsigned short Bh[128][40] __attribute__((aligned(16)));
    __shared__ unsigned short Bl[128][40] __attribute__((aligned(16)));
    const int tid  = threadIdx.x;
    const int wv   = tid >> 6, lane = tid & 63;
    const int quad = lane >> 4, l15 = lane & 15;
    const int m0 = blockIdx.y * 128, n0 = blockIdx.x * 128;
    const int wm = (wv >> 1) * 64, wn = (wv & 1) * 64;

    // staging: thread -> rows (srow, srow+64), k-group sk8
    const int srow = tid >> 2;          // 0..63
    const int sk8  = (tid & 3) * 8;     // 0,8,16,24

    int bn0 = n0 + srow;      if (bn0 > N_HID - 1) bn0 = N_HID - 1;
    int bn1 = n0 + srow + 64; if (bn1 > N_HID - 1) bn1 = N_HID - 1;

    const unsigned short* pxh0 = xh + (size_t)(m0 + srow) * KPAD + sk8;
    const unsigned short* pxh1 = xh + (size_t)(m0 + srow + 64) * KPAD + sk8;
    const unsigned short* pxl0 = xl + (size_t)(m0 + srow) * KPAD + sk8;
    const unsigned short* pxl1 = xl + (size_t)(m0 + srow + 64) * KPAD + sk8;
    const unsigned short* pwh0 = wh + (size_t)bn0 * KPAD + sk8;
    const unsigned short* pwh1 = wh + (size_t)bn1 * KPAD + sk8;
    const unsigned short* pwl0 = wl + (size_t)bn0 * KPAD + sk8;
    const unsigned short* pwl1 = wl + (size_t)bn1 * KPAD + sk8;

    floatx4 acc[4][4];
    #pragma unroll
    for (int a = 0; a < 4; ++a)
        #pragma unroll
        for (int b = 0; b < 4; ++b)
            acc[a][b] = (floatx4){0.f, 0.f, 0.f, 0.f};

    u16x8 rah0 = *(const u16x8*)(pxh0);
    u16x8 rah1 = *(const u16x8*)(pxh1);
    u16x8 ral0 = *(const u16x8*)(pxl0);
    u16x8 ral1 = *(const u16x8*)(pxl1);
    u16x8 rbh0 = *(const u16x8*)(pwh0);
    u16x8 rbh1 = *(const u16x8*)(pwh1);
    u16x8 rbl0 = *(const u16x8*)(pwl0);
    u16x8 rbl1 = *(const u16x8*)(pwl1);

    for (int k0 = 0; k0 < KPAD; k0 += 32) {
        __syncthreads();   // previous chunk's LDS reads complete
        *(u16x8*)&Ah[srow][sk8]      = rah0;
        *(u16x8*)&Ah[srow + 64][sk8] = rah1;
        *(u16x8*)&Al[srow][sk8]      = ral0;
        *(u16x8*)&Al[srow + 64][sk8] = ral1;
        *(u16x8*)&Bh[srow][sk8]      = rbh0;
        *(u16x8*)&Bh[srow + 64][sk8] = rbh1;
        *(u16x8*)&Bl[srow][sk8]      = rbl0;
        *(u16x8*)&Bl[srow + 64][sk8] = rbl1;
        __syncthreads();

        const int kn = (k0 + 32 < KPAD) ? (k0 + 32) : 0;   // last-iter dummy
        rah0 = *(const u16x8*)(pxh0 + kn);
        rah1 = *(const u16x8*)(pxh1 + kn);
        ral0 = *(const u16x8*)(pxl0 + kn);
        ral1 = *(const u16x8*)(pxl1 + kn);
        rbh0 = *(const u16x8*)(pwh0 + kn);
        rbh1 = *(const u16x8*)(pwh1 + kn);
        rbl0 = *(const u16x8*)(pwl0 + kn);
        rbl1 = *(const u16x8*)(pwl1 + kn);

        bf16x8 bhf[4], blf[4];
        #pragma unroll
        for (int ng = 0; ng < 4; ++ng) {
            const int br = wn + ng * 16 + l15;
            bhf[ng] = *(const bf16x8*)&Bh[br][quad * 8];
            blf[ng] = *(const bf16x8*)&Bl[br][quad * 8];
        }
        #pragma unroll
        for (int mg = 0; mg < 4; ++mg) {
            const int ar = wm + mg * 16 + l15;
            bf16x8 ah = *(const bf16x8*)&Ah[ar][quad * 8];
            bf16x8 al = *(const bf16x8*)&Al[ar][quad * 8];
            #pragma unroll
            for (int ng = 0; ng < 4; ++ng) {
                acc[mg][ng] = __builtin_amdgcn_mfma_f32_16x16x32_bf16(ah, bhf[ng], acc[mg][ng], 0, 0, 0);
                acc[mg][ng] = __builtin_amdgcn_mfma_f32_16x16x32_bf16(ah, blf[ng], acc[mg][ng], 0, 0, 0);
                acc[mg][ng] = __builtin_amdgcn_mfma_f32_16x16x32_bf16(al, bhf[ng], acc[mg][ng], 0, 0, 0);
            }
        }
    }

    // Epilogue: C/D layout col=lane&15 (n), row=quad*4+reg (m)  [m89/m91]
    #pragma unroll
    for (int ng = 0; ng < 4; ++ng) {
        const int n = n0 + wn + ng * 16 + l15;
        if (n < N_HID) {
            const float bv = b1[n];
            #pragma unroll
            for (int mg = 0; mg < 4; ++mg) {
                #pragma unroll
                for (int t = 0; t < 4; ++t) {
                    const int m = m0 + wm + mg * 16 + quad * 4 + t;
                    h[(size_t)m * N_HID + n] = acc[mg][ng][t] + bv;
                }
            }
        }
    }
}

// ---------------------------------------------------------------------------
// Phase 2: round-10 structure; the contested-element exact recompute is now
// double-buffered in 16-wide chunks (loads 16 ahead of the serial fmaf
// chain).  Serial k-ascending fp32 order EXACTLY preserved -> winner set
// bit-identical to rounds 2-10.
// ---------------------------------------------------------------------------
__global__ __launch_bounds__(256) void topk_logits_kernel(
        const float* __restrict__ h, const float* __restrict__ x,
        const float* __restrict__ w1, const float* __restrict__ b1,
        const float* __restrict__ boost, const float* __restrict__ w2t,
        const float* __restrict__ b2, float* __restrict__ out) {
    __shared__ unsigned shist[4 * 256] __attribute__((aligned(16)));
    __shared__ uint2 swin[4][K_WIN] __attribute__((aligned(16)));
    __shared__ unsigned scon_idx[4][64];
    __shared__ unsigned scon_h[4][64];
    __shared__ unsigned scon_k[4][64];
    const int wv   = threadIdx.x >> 6;
    const int lane = threadIdx.x & 63;
    const int row  = blockIdx.x * 4 + wv;
    unsigned* hist = &shist[wv * 256];

    swin[wv][lane] = make_uint2(0u, 0u);
    swin[wv][lane + 64] = make_uint2(0u, 0u);
    swin[wv][lane + 128] = make_uint2(0u, 0u);
    if (lane < 8) swin[wv][lane + 192] = make_uint2(0u, 0u);

    const float* hrow = h + (size_t)row * N_HID;
    float4 hreg[8];
    unsigned key[8][4];

    #pragma unroll
    for (int s = 0; s < 8; ++s) {
        const int idx4 = s * 64 + lane;
        if (idx4 < N_HID / 4) {
            float4 hv = *(const float4*)(hrow + idx4 * 4);
            float4 bv = *(const float4*)(boost + idx4 * 4);
            hreg[s] = hv;
            key[s][0] = mapkey(hv.x * bv.x);
            key[s][1] = mapkey(hv.y * bv.y);
            key[s][2] = mapkey(hv.z * bv.z);
            key[s][3] = mapkey(hv.w * bv.w);
        } else {
            hreg[s] = make_float4(0.f, 0.f, 0.f, 0.f);
            key[s][0] = key[s][1] = key[s][2] = key[s][3] = 0u;
        }
    }

    unsigned pref = 0u;
    int r = K_WIN;

    #pragma unroll
    for (int pass = 3; pass >= 0; --pass) {
        const int shift = pass * 8;
        const unsigned himask = (pass == 3) ? 0u : (0xFFFFFFFFu << (shift + 8));
        hist[lane] = 0u; hist[lane + 64] = 0u; hist[lane + 128] = 0u; hist[lane + 192] = 0u;
        __builtin_amdgcn_wave_barrier();
        #pragma unroll
        for (int s = 0; s < 8; ++s)
            #pragma unroll
            for (int j = 0; j < 4; ++j) {
                unsigned k = key[s][j];
                if (((k ^ pref) & himask) == 0u)
                    atomicAdd(&hist[(k >> shift) & 255u], 1u);
            }
        __builtin_amdgcn_wave_barrier();
        uint4 hv = *(const uint4*)&hist[lane * 4];
        unsigned tot = hv.x + hv.y + hv.z + hv.w;
        unsigned run = tot;
        #pragma unroll
        for (int off = 1; off < 64; off <<= 1) {
            unsigned t = (unsigned)__shfl_down((int)run, off);
            if (lane + off < 64) run += t;
        }
        const int above = (int)(run - tot);
        const int i3 = above + (int)hv.w;
        const int i2 = i3 + (int)hv.z;
        const int i1 = i2 + (int)hv.y;
        const int i0 = i1 + (int)hv.x;
        int fq = -1, fex = 0;
        if (i0 >= r && i1 < r)    { fq = 0; fex = i1; }
        if (i1 >= r && i2 < r)    { fq = 1; fex = i2; }
        if (i2 >= r && i3 < r)    { fq = 2; fex = i3; }
        if (i3 >= r && above < r) { fq = 3; fex = above; }
        unsigned long long fm = __ballot(fq >= 0);
        int src = __builtin_ctzll(fm);
        unsigned pack = (fq >= 0)
            ? (((unsigned)(lane * 4 + fq) << 16) | (unsigned)(r - fex)) : 0u;
        pack = (unsigned)__shfl((int)pack, src);
        pref |= (pack >> 16) << shift;
        r = (int)(pack & 0xFFFFu);
    }

    const float tval = unmapkey(pref);
    const unsigned kin  = mapkey(tval + EPS_MARGIN);
    const unsigned kout = mapkey(tval - EPS_MARGIN);

    int nsure = 0, ncon = 0;
    #pragma unroll
    for (int s = 0; s < 8; ++s) {
        const int idx4 = s * 64 + lane;
        const float* hp = (const float*)&hreg[s];
        #pragma unroll
        for (int j = 0; j < 4; ++j) {
            unsigned k = key[s][j];
            bool sure = (k > kin);
            bool cont = (!sure) && (k >= kout);
            unsigned long long sm = __ballot(sure);
            unsigned long long cm = __ballot(cont);
            const unsigned long long lt = (1ull << lane) - 1ull;
            if (sure) {
                int pos = nsure + __popcll(sm & lt);
                if (pos < K_WIN)
                    swin[wv][pos] = make_uint2((unsigned)(idx4 * 4 + j),
                                               __float_as_uint(hp[j]));
            }
            if (cont) {
                int pos = ncon + __popcll(cm & lt);
                if (pos < 64) {
                    scon_idx[wv][pos] = (unsigned)(idx4 * 4 + j);
                    scon_h[wv][pos]   = __float_as_uint(hp[j]);
                }
            }
            nsure += __popcll(sm);
            ncon  += __popcll(cm);
        }
    }
    if (ncon > 64) ncon = 64;
    __builtin_amdgcn_wave_barrier();

    // exact canonical-fp32 recompute, double-buffered 16-wide chunks
    unsigned myidx = 0, kex = 0;
    const bool act = (lane < ncon);
    if (act) {
        myidx = scon_idx[wv][lane];
        const float* xr = x + (size_t)row * IN_DIM;
        const float* wr = w1 + (size_t)myidx * IN_DIM;
        float a = 0.f;
        float4 bx[2][4], bw[2][4];
        #pragma unroll
        for (int q = 0; q < 4; ++q) {
            bx[0][q] = *(const float4*)(xr + q * 4);
            bw[0][q] = *(const float4*)(wr + q * 4);
        }
        for (int c = 0; c < IN_DIM / 16; ++c) {          // 49 chunks
            const int cb = c & 1, nb = cb ^ 1;
            if (c + 1 < IN_DIM / 16) {
                #pragma unroll
                for (int q = 0; q < 4; ++q) {
                    bx[nb][q] = *(const float4*)(xr + (c + 1) * 16 + q * 4);
                    bw[nb][q] = *(const float4*)(wr + (c + 1) * 16 + q * 4);
                }
            }
            #pragma unroll
            for (int q = 0; q < 4; ++q) {                // k ascending: exact order
                a = fmaf(bx[cb][q].x, bw[cb][q].x, a);
                a = fmaf(bx[cb][q].y, bw[cb][q].y, a);
                a = fmaf(bx[cb][q].z, bw[cb][q].z, a);
                a = fmaf(bx[cb][q].w, bw[cb][q].w, a);
            }
        }
        const float bex = (a + b1[myidx]) * boost[myidx];
        kex = mapkey(bex);
        scon_k[wv][lane] = kex;
    }
    __builtin_amdgcn_wave_barrier();

    const int nsel = K_WIN - nsure;
    if (act) {
        int rnk = 0;
        for (int q = 0; q < ncon; ++q) {
            unsigned kq = scon_k[wv][q];
            unsigned iq = scon_idx[wv][q];
            rnk += (int)((kq > kex) || (kq == kex && iq < myidx));
        }
        if (rnk < nsel) {
            int pos = nsure + rnk;
            if (pos >= 0 && pos < K_WIN)
                swin[wv][pos] = make_uint2(myidx, scon_h[wv][lane]);
        }
    }
    __builtin_amdgcn_wave_barrier();

    float l[10];
    #pragma unroll
    for (int cc = 0; cc < 10; ++cc) l[cc] = 0.f;
    #pragma unroll
    for (int t = 0; t < 4; ++t) {
        const bool a2 = (t < 3) || (lane < K_WIN - 192);
        if (a2) {
            const uint2 wrec = swin[wv][t * 64 + lane];
            const float hv = __uint_as_float(wrec.y);
            const float* wr = w2t + (size_t)wrec.x * 12;
            float4 wa = *(const float4*)wr;
            float4 wb = *(const float4*)(wr + 4);
            float2 wc = *(const float2*)(wr + 8);
            l[0] = fmaf(hv, wa.x, l[0]);
            l[1] = fmaf(hv, wa.y, l[1]);
            l[2] = fmaf(hv, wa.z, l[2]);
            l[3] = fmaf(hv, wa.w, l[3]);
            l[4] = fmaf(hv, wb.x, l[4]);
            l[5] = fmaf(hv, wb.y, l[5]);
            l[6] = fmaf(hv, wb.z, l[6]);
            l[7] = fmaf(hv, wb.w, l[7]);
            l[8] = fmaf(hv, wc.x, l[8]);
            l[9] = fmaf(hv, wc.y, l[9]);
        }
    }
    #pragma unroll
    for (int off = 32; off > 0; off >>= 1)
        #pragma unroll
        for (int cc = 0; cc < 10; ++cc)
            l[cc] += __shfl_down(l[cc], off);

    if (lane == 0) {
        float lg[10];
        #pragma unroll
        for (int cc = 0; cc < 10; ++cc) lg[cc] = l[cc] + b2[cc];
        float mx = lg[0];
        #pragma unroll
        for (int cc = 1; cc < 10; ++cc) mx = fmaxf(mx, lg[cc]);
        float s = 0.f;
        #pragma unroll
        for (int cc = 0; cc < 10; ++cc) s += expf(lg[cc] - mx);
        const float lse = mx + logf(s);
        float* orow = out + (size_t)row * 10;
        #pragma unroll
        for (int cc = 0; cc < 10; ++cc) orow[cc] = lg[cc] - lse;
    }
}

// ---------------------------------------------------------------------------
extern "C" void kernel_launch(void* const* d_in, const int* in_sizes, int n_in,
                              void* d_out, int out_size, void* d_ws, size_t ws_size,
                              hipStream_t stream) {
    const float* x    = (const float*)d_in[0];
    const float* w1   = (const float*)d_in[1];
    const float* b1   = (const float*)d_in[2];
    const float* w2   = (const float*)d_in[3];
    const float* b2   = (const float*)d_in[4];
    const float* duty = (const float*)d_in[5];
    float* out = (float*)d_out;

    const size_t hbytes  = (size_t)B_ROWS * N_HID * sizeof(float);   // 131.072 MB
    const size_t xsbytes = (size_t)B_ROWS * KPAD * 2;                // 26.214 MB
    const size_t wsbytes = (size_t)N_HID * KPAD * 2;                 //  3.200 MB
    char* p = (char*)d_ws;
    float* h     = (float*)p;                    p += hbytes;
    float* boost = (float*)p;                    p += 8192;
    float* w2t   = (float*)p;                    p += 98304;
    unsigned short* xh = (unsigned short*)p;     p += xsbytes;
    unsigned short* xl = (unsigned short*)p;     p += xsbytes;
    unsigned short* wh = (unsigned short*)p;     p += wsbytes;
    unsigned short* wl = (unsigned short*)p;     p += wsbytes;
    // total ~190 MB <= ws (256 MiB per round-1 fill evidence)

    prep_kernel<<<(N_HID * 10 + 255) / 256, 256, 0, stream>>>(duty, w2, boost, w2t);
    split_kernel<<<(XG + WG + 255) / 256, 256, 0, stream>>>(x, w1, xh, xl, wh, wl);
    gemm_mfma_kernel<<<dim3(16, 128), 256, 0, stream>>>(xh, xl, wh, wl, b1, h);
    topk_logits_kernel<<<B_ROWS / 4, 256, 0, stream>>>(h, x, w1, b1, boost, w2t, b2, out);
}

// Round 12
// 377.110 us; speedup vs baseline: 2.4268x; 2.4268x over previous
//
#include <hip/hip_runtime.h>
#include <cmath>

#define B_ROWS 16384
#define IN_DIM 784
#define N_HID  2000
#define K_WIN  200
#define KPAD   800
#define EPS_MARGIN 1.5e-3f

typedef __attribute__((ext_vector_type(8))) short bf16x8;            // 8 bf16 = 4 VGPR
typedef __attribute__((ext_vector_type(8))) unsigned short u16x8;    // 16 B
typedef __attribute__((ext_vector_type(4))) float floatx4;           // MFMA C/D

__device__ inline unsigned short bf16_rn_bits(float f) {
    unsigned u = __float_as_uint(f);
    return (unsigned short)((u + 0x7FFFu + ((u >> 16) & 1u)) >> 16);
}
__device__ inline unsigned mapkey(float f) {
    unsigned u = __float_as_uint(f);
    return (u >> 31) ? ~u : (u | 0x80000000u);
}
__device__ inline float unmapkey(unsigned k) {
    unsigned u = (k & 0x80000000u) ? (k & 0x7FFFFFFFu) : ~k;
    return __uint_as_float(u);
}

// ---------------------------------------------------------------------------
// Phase 0a: boost + w2 transpose
// ---------------------------------------------------------------------------
__global__ __launch_bounds__(256) void prep_kernel(const float* __restrict__ duty,
                                                   const float* __restrict__ w2,
                                                   float* __restrict__ boost,
                                                   float* __restrict__ w2t) {
    int t = blockIdx.x * 256 + threadIdx.x;
    if (t < N_HID) boost[t] = expf(0.1f - duty[t]);
    if (t < N_HID * 10) {
        int i = t / 10, c = t - i * 10;
        w2t[i * 12 + c] = w2[c * N_HID + i];
    }
}

// ---------------------------------------------------------------------------
// Phase 0b: one-time fp32 -> bf16 hi/lo split of x and w1 (K padded to 800).
// ---------------------------------------------------------------------------
#define XG (B_ROWS * (KPAD / 4))
#define WG (N_HID  * (KPAD / 4))
__global__ __launch_bounds__(256) void split_kernel(
        const float* __restrict__ x, const float* __restrict__ w1,
        unsigned short* __restrict__ xh, unsigned short* __restrict__ xl,
        unsigned short* __restrict__ wh, unsigned short* __restrict__ wl) {
    int t = blockIdx.x * 256 + threadIdx.x;
    const float* src;
    unsigned short *dh, *dl;
    int row, g;
    if (t < XG) {
        row = t / (KPAD / 4); g = t - row * (KPAD / 4);
        src = x + (size_t)row * IN_DIM;
        dh = xh + (size_t)row * KPAD; dl = xl + (size_t)row * KPAD;
    } else if (t < XG + WG) {
        int s = t - XG;
        row = s / (KPAD / 4); g = s - row * (KPAD / 4);
        src = w1 + (size_t)row * IN_DIM;
        dh = wh + (size_t)row * KPAD; dl = wl + (size_t)row * KPAD;
    } else return;
    const int kq = g * 4;
    float4 v = make_float4(0.f, 0.f, 0.f, 0.f);
    if (kq + 3 < IN_DIM) v = *(const float4*)(src + kq);
    const float* vp = (const float*)&v;
    unsigned short hs[4], ls[4];
    #pragma unroll
    for (int q = 0; q < 4; ++q) {
        hs[q] = bf16_rn_bits(vp[q]);
        float hf = __uint_as_float(((unsigned)hs[q]) << 16);
        ls[q] = bf16_rn_bits(vp[q] - hf);
    }
    *(ushort4*)(dh + kq) = make_ushort4(hs[0], hs[1], hs[2], hs[3]);
    *(ushort4*)(dl + kq) = make_ushort4(ls[0], ls[1], ls[2], ls[3]);
}

// ---------------------------------------------------------------------------
// Phase 1: h' = x @ W1^T + b1 via split-bf16 MFMA (hh + hl + lh), streaming
// pre-split bf16 arrays.  Round-11 version VERBATIM (h' bit-identical).
// ---------------------------------------------------------------------------
__global__ __launch_bounds__(256) void gemm_mfma_kernel(
        const unsigned short* __restrict__ xh, const unsigned short* __restrict__ xl,
        const unsigned short* __restrict__ wh, const unsigned short* __restrict__ wl,
        const float* __restrict__ b1, float* __restrict__ h) {
    __shared__ unsigned short Ah[128][40] __attribute__((aligned(16)));
    __shared__ unsigned short Al[128][40] __attribute__((aligned(16)));
    __shared__ unsigned short Bh[128][40] __attribute__((aligned(16)));
    __shared__ unsigned short Bl[128][40] __attribute__((aligned(16)));
    const int tid  = threadIdx.x;
    const int wv   = tid >> 6, lane = tid & 63;
    const int quad = lane >> 4, l15 = lane & 15;
    const int m0 = blockIdx.y * 128, n0 = blockIdx.x * 128;
    const int wm = (wv >> 1) * 64, wn = (wv & 1) * 64;

    const int srow = tid >> 2;
    const int sk8  = (tid & 3) * 8;

    int bn0 = n0 + srow;      if (bn0 > N_HID - 1) bn0 = N_HID - 1;
    int bn1 = n0 + srow + 64; if (bn1 > N_HID - 1) bn1 = N_HID - 1;

    const unsigned short* pxh0 = xh + (size_t)(m0 + srow) * KPAD + sk8;
    const unsigned short* pxh1 = xh + (size_t)(m0 + srow + 64) * KPAD + sk8;
    const unsigned short* pxl0 = xl + (size_t)(m0 + srow) * KPAD + sk8;
    const unsigned short* pxl1 = xl + (size_t)(m0 + srow + 64) * KPAD + sk8;
    const unsigned short* pwh0 = wh + (size_t)bn0 * KPAD + sk8;
    const unsigned short* pwh1 = wh + (size_t)bn1 * KPAD + sk8;
    const unsigned short* pwl0 = wl + (size_t)bn0 * KPAD + sk8;
    const unsigned short* pwl1 = wl + (size_t)bn1 * KPAD + sk8;

    floatx4 acc[4][4];
    #pragma unroll
    for (int a = 0; a < 4; ++a)
        #pragma unroll
        for (int b = 0; b < 4; ++b)
            acc[a][b] = (floatx4){0.f, 0.f, 0.f, 0.f};

    u16x8 rah0 = *(const u16x8*)(pxh0);
    u16x8 rah1 = *(const u16x8*)(pxh1);
    u16x8 ral0 = *(const u16x8*)(pxl0);
    u16x8 ral1 = *(const u16x8*)(pxl1);
    u16x8 rbh0 = *(const u16x8*)(pwh0);
    u16x8 rbh1 = *(const u16x8*)(pwh1);
    u16x8 rbl0 = *(const u16x8*)(pwl0);
    u16x8 rbl1 = *(const u16x8*)(pwl1);

    for (int k0 = 0; k0 < KPAD; k0 += 32) {
        __syncthreads();
        *(u16x8*)&Ah[srow][sk8]      = rah0;
        *(u16x8*)&Ah[srow + 64][sk8] = rah1;
        *(u16x8*)&Al[srow][sk8]      = ral0;
        *(u16x8*)&Al[srow + 64][sk8] = ral1;
        *(u16x8*)&Bh[srow][sk8]      = rbh0;
        *(u16x8*)&Bh[srow + 64][sk8] = rbh1;
        *(u16x8*)&Bl[srow][sk8]      = rbl0;
        *(u16x8*)&Bl[srow + 64][sk8] = rbl1;
        __syncthreads();

        const int kn = (k0 + 32 < KPAD) ? (k0 + 32) : 0;
        rah0 = *(const u16x8*)(pxh0 + kn);
        rah1 = *(const u16x8*)(pxh1 + kn);
        ral0 = *(const u16x8*)(pxl0 + kn);
        ral1 = *(const u16x8*)(pxl1 + kn);
        rbh0 = *(const u16x8*)(pwh0 + kn);
        rbh1 = *(const u16x8*)(pwh1 + kn);
        rbl0 = *(const u16x8*)(pwl0 + kn);
        rbl1 = *(const u16x8*)(pwl1 + kn);

        bf16x8 bhf[4], blf[4];
        #pragma unroll
        for (int ng = 0; ng < 4; ++ng) {
            const int br = wn + ng * 16 + l15;
            bhf[ng] = *(const bf16x8*)&Bh[br][quad * 8];
            blf[ng] = *(const bf16x8*)&Bl[br][quad * 8];
        }
        #pragma unroll
        for (int mg = 0; mg < 4; ++mg) {
            const int ar = wm + mg * 16 + l15;
            bf16x8 ah = *(const bf16x8*)&Ah[ar][quad * 8];
            bf16x8 al = *(const bf16x8*)&Al[ar][quad * 8];
            #pragma unroll
            for (int ng = 0; ng < 4; ++ng) {
                acc[mg][ng] = __builtin_amdgcn_mfma_f32_16x16x32_bf16(ah, bhf[ng], acc[mg][ng], 0, 0, 0);
                acc[mg][ng] = __builtin_amdgcn_mfma_f32_16x16x32_bf16(ah, blf[ng], acc[mg][ng], 0, 0, 0);
                acc[mg][ng] = __builtin_amdgcn_mfma_f32_16x16x32_bf16(al, bhf[ng], acc[mg][ng], 0, 0, 0);
            }
        }
    }

    #pragma unroll
    for (int ng = 0; ng < 4; ++ng) {
        const int n = n0 + wn + ng * 16 + l15;
        if (n < N_HID) {
            const float bv = b1[n];
            #pragma unroll
            for (int mg = 0; mg < 4; ++mg) {
                #pragma unroll
                for (int t = 0; t < 4; ++t) {
                    const int m = m0 + wm + mg * 16 + quad * 4 + t;
                    h[(size_t)m * N_HID + n] = acc[mg][ng][t] + bv;
                }
            }
        }
    }
}

// ---------------------------------------------------------------------------
// Phase 2: one row per wave, 4 rows/block, zero __syncthreads.
// Radix select on h'*boost keys -> margin classification (sure / contested).
// NEW: contested elements re-ranked by WAVE-COOPERATIVE FP64 dot products
// (order-independent, coalesced x/w1 reads, fp64 shuffle-reduce) — removes
// round-11's serial latency-exposed chain.  Margin EPS covers
// |h'-h_true|*boost (~2e-4 << 1.5e-3), so combined set == exact fp64 top-k.
// ---------------------------------------------------------------------------
__global__ __launch_bounds__(256) void topk_logits_kernel(
        const float* __restrict__ h, const float* __restrict__ x,
        const float* __restrict__ w1, const float* __restrict__ b1,
        const float* __restrict__ boost, const float* __restrict__ w2t,
        const float* __restrict__ b2, float* __restrict__ out) {
    __shared__ unsigned shist[4 * 256] __attribute__((aligned(16)));
    __shared__ uint2 swin[4][K_WIN] __attribute__((aligned(16)));
    __shared__ unsigned scon_idx[4][64];
    __shared__ unsigned scon_h[4][64];
    __shared__ unsigned long long scon_k64[4][64] __attribute__((aligned(16)));
    const int wv   = threadIdx.x >> 6;
    const int lane = threadIdx.x & 63;
    const int row  = blockIdx.x * 4 + wv;
    unsigned* hist = &shist[wv * 256];

    swin[wv][lane] = make_uint2(0u, 0u);
    swin[wv][lane + 64] = make_uint2(0u, 0u);
    swin[wv][lane + 128] = make_uint2(0u, 0u);
    if (lane < 8) swin[wv][lane + 192] = make_uint2(0u, 0u);

    const float* hrow = h + (size_t)row * N_HID;
    float4 hreg[8];
    unsigned key[8][4];

    #pragma unroll
    for (int s = 0; s < 8; ++s) {
        const int idx4 = s * 64 + lane;
        if (idx4 < N_HID / 4) {
            float4 hv = *(const float4*)(hrow + idx4 * 4);
            float4 bv = *(const float4*)(boost + idx4 * 4);
            hreg[s] = hv;
            key[s][0] = mapkey(hv.x * bv.x);
            key[s][1] = mapkey(hv.y * bv.y);
            key[s][2] = mapkey(hv.z * bv.z);
            key[s][3] = mapkey(hv.w * bv.w);
        } else {
            hreg[s] = make_float4(0.f, 0.f, 0.f, 0.f);
            key[s][0] = key[s][1] = key[s][2] = key[s][3] = 0u;
        }
    }

    unsigned pref = 0u;
    int r = K_WIN;

    #pragma unroll
    for (int pass = 3; pass >= 0; --pass) {
        const int shift = pass * 8;
        const unsigned himask = (pass == 3) ? 0u : (0xFFFFFFFFu << (shift + 8));
        hist[lane] = 0u; hist[lane + 64] = 0u; hist[lane + 128] = 0u; hist[lane + 192] = 0u;
        __builtin_amdgcn_wave_barrier();
        #pragma unroll
        for (int s = 0; s < 8; ++s)
            #pragma unroll
            for (int j = 0; j < 4; ++j) {
                unsigned k = key[s][j];
                if (((k ^ pref) & himask) == 0u)
                    atomicAdd(&hist[(k >> shift) & 255u], 1u);
            }
        __builtin_amdgcn_wave_barrier();
        uint4 hv = *(const uint4*)&hist[lane * 4];
        unsigned tot = hv.x + hv.y + hv.z + hv.w;
        unsigned run = tot;
        #pragma unroll
        for (int off = 1; off < 64; off <<= 1) {
            unsigned t = (unsigned)__shfl_down((int)run, off);
            if (lane + off < 64) run += t;
        }
        const int above = (int)(run - tot);
        const int i3 = above + (int)hv.w;
        const int i2 = i3 + (int)hv.z;
        const int i1 = i2 + (int)hv.y;
        const int i0 = i1 + (int)hv.x;
        int fq = -1, fex = 0;
        if (i0 >= r && i1 < r)    { fq = 0; fex = i1; }
        if (i1 >= r && i2 < r)    { fq = 1; fex = i2; }
        if (i2 >= r && i3 < r)    { fq = 2; fex = i3; }
        if (i3 >= r && above < r) { fq = 3; fex = above; }
        unsigned long long fm = __ballot(fq >= 0);
        int src = __builtin_ctzll(fm);
        unsigned pack = (fq >= 0)
            ? (((unsigned)(lane * 4 + fq) << 16) | (unsigned)(r - fex)) : 0u;
        pack = (unsigned)__shfl((int)pack, src);
        pref |= (pack >> 16) << shift;
        r = (int)(pack & 0xFFFFu);
    }

    const float tval = unmapkey(pref);
    const unsigned kin  = mapkey(tval + EPS_MARGIN);
    const unsigned kout = mapkey(tval - EPS_MARGIN);

    int nsure = 0, ncon = 0;
    #pragma unroll
    for (int s = 0; s < 8; ++s) {
        const int idx4 = s * 64 + lane;
        const float* hp = (const float*)&hreg[s];
        #pragma unroll
        for (int j = 0; j < 4; ++j) {
            unsigned k = key[s][j];
            bool sure = (k > kin);
            bool cont = (!sure) && (k >= kout);
            unsigned long long sm = __ballot(sure);
            unsigned long long cm = __ballot(cont);
            const unsigned long long lt = (1ull << lane) - 1ull;
            if (sure) {
                int pos = nsure + __popcll(sm & lt);
                if (pos < K_WIN)
                    swin[wv][pos] = make_uint2((unsigned)(idx4 * 4 + j),
                                               __float_as_uint(hp[j]));
            }
            if (cont) {
                int pos = ncon + __popcll(cm & lt);
                if (pos < 64) {
                    scon_idx[wv][pos] = (unsigned)(idx4 * 4 + j);
                    scon_h[wv][pos]   = __float_as_uint(hp[j]);
                }
            }
            nsure += __popcll(sm);
            ncon  += __popcll(cm);
        }
    }
    if (ncon > 64) ncon = 64;
    __builtin_amdgcn_wave_barrier();

    // -------- wave-cooperative fp64 recompute of contested elements --------
    // preload x row: lane handles k = t*64 + lane  (coalesced)
    {
        const float* xr = x + (size_t)row * IN_DIM;
        float xreg[13];
        #pragma unroll
        for (int t = 0; t < 13; ++t) {
            const int k = t * 64 + lane;
            xreg[t] = (k < IN_DIM) ? xr[k] : 0.f;
        }
        for (int q = 0; q < ncon; ++q) {          // ncon wave-uniform
            const unsigned idx = scon_idx[wv][q]; // uniform -> broadcast
            const float* wr = w1 + (size_t)idx * IN_DIM;
            double part = 0.0;
            #pragma unroll
            for (int t = 0; t < 13; ++t) {
                const int k = t * 64 + lane;
                if (k < IN_DIM)
                    part = fma((double)xreg[t], (double)wr[k], part);
            }
            #pragma unroll
            for (int off = 32; off > 0; off >>= 1)
                part += __shfl_down(part, off);
            if (lane == 0) {
                const double bex = (part + (double)b1[idx]) * (double)boost[idx];
                unsigned long long u = (unsigned long long)__double_as_longlong(bex);
                u = (u >> 63) ? ~u : (u | 0x8000000000000000ULL);
                scon_k64[wv][q] = u;
            }
        }
    }
    __builtin_amdgcn_wave_barrier();

    // exact ranking among contested by fp64 key (index ties -> lower first)
    const int nsel = K_WIN - nsure;
    if (lane < ncon) {
        const unsigned long long kex = scon_k64[wv][lane];
        const unsigned myidx = scon_idx[wv][lane];
        int rnk = 0;
        for (int q = 0; q < ncon; ++q) {
            const unsigned long long kq = scon_k64[wv][q];
            rnk += (int)((kq > kex) || (kq == kex && scon_idx[wv][q] < myidx));
        }
        if (rnk < nsel) {
            const int pos = nsure + rnk;
            if (pos >= 0 && pos < K_WIN)
                swin[wv][pos] = make_uint2(myidx, scon_h[wv][lane]);
        }
    }
    __builtin_amdgcn_wave_barrier();

    // uniform gather over exactly K_WIN winners
    float l[10];
    #pragma unroll
    for (int cc = 0; cc < 10; ++cc) l[cc] = 0.f;
    #pragma unroll
    for (int t = 0; t < 4; ++t) {
        const bool a2 = (t < 3) || (lane < K_WIN - 192);
        if (a2) {
            const uint2 wrec = swin[wv][t * 64 + lane];
            const float hv = __uint_as_float(wrec.y);
            const float* wr = w2t + (size_t)wrec.x * 12;
            float4 wa = *(const float4*)wr;
            float4 wb = *(const float4*)(wr + 4);
            float2 wc = *(const float2*)(wr + 8);
            l[0] = fmaf(hv, wa.x, l[0]);
            l[1] = fmaf(hv, wa.y, l[1]);
            l[2] = fmaf(hv, wa.z, l[2]);
            l[3] = fmaf(hv, wa.w, l[3]);
            l[4] = fmaf(hv, wb.x, l[4]);
            l[5] = fmaf(hv, wb.y, l[5]);
            l[6] = fmaf(hv, wb.z, l[6]);
            l[7] = fmaf(hv, wb.w, l[7]);
            l[8] = fmaf(hv, wc.x, l[8]);
            l[9] = fmaf(hv, wc.y, l[9]);
        }
    }
    #pragma unroll
    for (int off = 32; off > 0; off >>= 1)
        #pragma unroll
        for (int cc = 0; cc < 10; ++cc)
            l[cc] += __shfl_down(l[cc], off);

    if (lane == 0) {
        float lg[10];
        #pragma unroll
        for (int cc = 0; cc < 10; ++cc) lg[cc] = l[cc] + b2[cc];
        float mx = lg[0];
        #pragma unroll
        for (int cc = 1; cc < 10; ++cc) mx = fmaxf(mx, lg[cc]);
        float s = 0.f;
        #pragma unroll
        for (int cc = 0; cc < 10; ++cc) s += expf(lg[cc] - mx);
        const float lse = mx + logf(s);
        float* orow = out + (size_t)row * 10;
        #pragma unroll
        for (int cc = 0; cc < 10; ++cc) orow[cc] = lg[cc] - lse;
    }
}

// ---------------------------------------------------------------------------
extern "C" void kernel_launch(void* const* d_in, const int* in_sizes, int n_in,
                              void* d_out, int out_size, void* d_ws, size_t ws_size,
                              hipStream_t stream) {
    const float* x    = (const float*)d_in[0];
    const float* w1   = (const float*)d_in[1];
    const float* b1   = (const float*)d_in[2];
    const float* w2   = (const float*)d_in[3];
    const float* b2   = (const float*)d_in[4];
    const float* duty = (const float*)d_in[5];
    float* out = (float*)d_out;

    const size_t hbytes  = (size_t)B_ROWS * N_HID * sizeof(float);   // 131.072 MB
    const size_t xsbytes = (size_t)B_ROWS * KPAD * 2;                // 26.214 MB
    const size_t wsbytes = (size_t)N_HID * KPAD * 2;                 //  3.200 MB
    char* p = (char*)d_ws;
    float* h     = (float*)p;                    p += hbytes;
    float* boost = (float*)p;                    p += 8192;
    float* w2t   = (float*)p;                    p += 98304;
    unsigned short* xh = (unsigned short*)p;     p += xsbytes;
    unsigned short* xl = (unsigned short*)p;     p += xsbytes;
    unsigned short* wh = (unsigned short*)p;     p += wsbytes;
    unsigned short* wl = (unsigned short*)p;     p += wsbytes;

    prep_kernel<<<(N_HID * 10 + 255) / 256, 256, 0, stream>>>(duty, w2, boost, w2t);
    split_kernel<<<(XG + WG + 255) / 256, 256, 0, stream>>>(x, w1, xh, xl, wh, wl);
    gemm_mfma_kernel<<<dim3(16, 128), 256, 0, stream>>>(xh, xl, wh, wl, b1, h);
    topk_logits_kernel<<<B_ROWS / 4, 256, 0, stream>>>(h, x, w1, b1, boost, w2t, b2, out);
}